// Round 5
// baseline (450.131 us; speedup 1.0000x reference)
//
#include <hip/hip_runtime.h>

#define NEIGHB 12
#define HIDD 128
#define CAP 40

typedef _Float16 half8 __attribute__((ext_vector_type(8)));
typedef float f32x4 __attribute__((ext_vector_type(4)));

// ---------------------------------------------------------------------------
// One-shot weight convert: 4 pairs (Wl,Wr) f32 -> [256][Kp] f16 zero-padded.
// ---------------------------------------------------------------------------
__global__ __launch_bounds__(256) void cvt_all(
    const float* __restrict__ W1b, const float* __restrict__ W1br, _Float16* __restrict__ O1b,
    const float* __restrict__ W1a, const float* __restrict__ W1ar, _Float16* __restrict__ O1a,
    const float* __restrict__ W2b, const float* __restrict__ W2br, _Float16* __restrict__ O2b,
    const float* __restrict__ W2a, const float* __restrict__ W2ar, _Float16* __restrict__ O2a) {
    int blk = blockIdx.x;
    const float *Wl, *Wr; _Float16* out; int K, Kp, base;
    if (blk < 512)       { Wl = W1b; Wr = W1br; out = O1b; K = 480;  Kp = 512;  base = 0; }
    else if (blk < 1984) { Wl = W1a; Wr = W1ar; out = O1a; K = 1440; Kp = 1472; base = 512; }
    else if (blk < 2112) { Wl = W2b; Wr = W2br; out = O2b; K = 128;  Kp = 128;  base = 1984; }
    else                 { Wl = W2a; Wr = W2ar; out = O2a; K = 128;  Kp = 128;  base = 2112; }
    int idx = (blk - base) * 256 + threadIdx.x;
    int n = idx / Kp, k = idx - n * Kp;
    float v = 0.f;
    if (k < K) v = (n < HIDD) ? Wl[(size_t)n * K + k] : Wr[(size_t)(n - HIDD) * K + k];
    out[idx] = (_Float16)v;
}

// ---------------------------------------------------------------------------
// MFMA GEMM with fused GBF expansion, raw rows cached in LDS.
// MODE 0: A = f16 [rows, KP] direct.
// MODE 1: A = gbf(bond f32 [rows,12]),  K=480,  SUB=40 (granule never crosses)
// MODE 2: A = gbf(angle f32 [rows,144]), K=1440, SUB=10 (crosses <= 1)
// NS = N-split (1: block covers all 256 cols, 2: half). Block 256 thr/4 waves.
// Tile 64(M) x (256/NS)(N); wave tile 64 x (64/NS); BK=64.
// LDS XOR swizzle: 16B granule g at g ^ (row & 7).
// ---------------------------------------------------------------------------
template <int MODE, int KTOT, int KP, int NS>
__global__ __launch_bounds__(256) void gemm_f16(
    const void* __restrict__ Ain, const _Float16* __restrict__ Wt,
    _Float16* __restrict__ Cl, _Float16* __restrict__ Cr, int rows) {
    constexpr int SUB  = (MODE == 2) ? 10 : 40;
    constexpr int RAWC = (MODE == 2) ? 144 : 12;
    constexpr int RST  = (MODE == 2) ? 148 : 12;   // LDS raw stride (f32)
    constexpr float MU0 = (MODE == 2) ? -1.0f : 0.0f;
    constexpr float DMU = (MODE == 2) ? (2.0f / 9.0f) : (8.0f / 39.0f);
    constexpr int BN = 256 / NS;   // block n-width
    constexpr int NB = BN / 64;    // n-frags per wave (4 or 2)

    __shared__ __align__(16) _Float16 As[64 * 64];
    __shared__ __align__(16) _Float16 Bs[BN * 64];
    __shared__ __align__(16) float rawS[(MODE != 0) ? 64 * RST : 4];

    const int tid = threadIdx.x;
    const int lane = tid & 63;
    const int wave = tid >> 6;
    const int nHalf = (NS == 2) ? ((int)blockIdx.x & 1) : 0;
    const int mb = (NS == 2) ? ((int)blockIdx.x >> 1) : (int)blockIdx.x;
    const int iBase = mb * 64;

    // ---- prologue: raw rows -> LDS (once) ----
    if (MODE != 0) {
        if (iBase + 64 <= rows) {
            const float* gsrc = (const float*)Ain + (size_t)iBase * RAWC;
            constexpr int NV4 = 64 * RAWC / 4;
#pragma unroll
            for (int q = 0; q < (NV4 + 255) / 256; ++q) {
                int idx = tid + 256 * q;
                if (NV4 % 256 == 0 || idx < NV4) {
                    int r = idx / (RAWC / 4);
                    int c4 = idx - r * (RAWC / 4);
                    float4 v = *reinterpret_cast<const float4*>(gsrc + (size_t)idx * 4);
                    *reinterpret_cast<float4*>(&rawS[r * RST + c4 * 4]) = v;
                }
            }
        } else {
            for (int idx = tid; idx < 64 * RAWC; idx += 256) {
                int r = idx / RAWC, c = idx - r * RAWC;
                int gi = iBase + r;
                rawS[r * RST + c] = (gi < rows) ? ((const float*)Ain)[(size_t)gi * RAWC + c] : 0.f;
            }
        }
        __syncthreads();
    }

    f32x4 acc[4][NB];
#pragma unroll
    for (int a = 0; a < 4; ++a)
#pragma unroll
        for (int b = 0; b < NB; ++b)
#pragma unroll
            for (int r = 0; r < 4; ++r) acc[a][b][r] = 0.f;

    for (int kc = 0; kc < KP; kc += 64) {
        __syncthreads();
        // ---- stage A tile [64][64]: 512 granules, 2 per thread ----
#pragma unroll
        for (int q = 0; q < 2; ++q) {
            int idx = tid + 256 * q;
            int m = idx >> 3, g = idx & 7;
            half8 v;
            if (MODE == 0) {
                int gi = min(iBase + m, rows - 1);
                v = *reinterpret_cast<const half8*>((const _Float16*)Ain + (size_t)gi * KP + kc + g * 8);
            } else {
                int k0 = kc + g * 8;
                if (k0 < KTOT) {
                    int j0 = k0 / SUB, t0 = k0 - j0 * SUB;
                    float r0 = rawS[m * RST + j0];
                    float r1 = (MODE == 2 && t0 + 7 >= SUB) ? rawS[m * RST + j0 + 1] : r0;
#pragma unroll
                    for (int e2 = 0; e2 < 8; ++e2) {
                        int t = t0 + e2;
                        bool c2 = (t >= SUB);
                        float d = (c2 ? r1 : r0) - (MU0 + (float)(c2 ? t - SUB : t) * DMU);
                        v[e2] = (_Float16)__expf(-25.f * d * d);
                    }
                } else {
#pragma unroll
                    for (int e2 = 0; e2 < 8; ++e2) v[e2] = (_Float16)0.f;
                }
            }
            *reinterpret_cast<half8*>(As + m * 64 + ((g ^ (m & 7)) << 3)) = v;
        }
        // ---- stage B tile [BN][64]: BN*8 granules ----
#pragma unroll
        for (int q = 0; q < BN / 32; ++q) {
            int idx = tid + 256 * q;
            int n = idx >> 3, g = idx & 7;
            half8 v = *reinterpret_cast<const half8*>(
                Wt + (size_t)(nHalf * BN + n) * KP + kc + g * 8);
            *reinterpret_cast<half8*>(Bs + n * 64 + ((g ^ (n & 7)) << 3)) = v;
        }
        __syncthreads();
        // ---- compute: 2 sub-steps of K=32 ----
#pragma unroll
        for (int s = 0; s < 2; ++s) {
            int cg = s * 4 + (lane >> 4);
            half8 af[4], bf[NB];
#pragma unroll
            for (int a = 0; a < 4; ++a) {
                int m = a * 16 + (lane & 15);
                af[a] = *reinterpret_cast<const half8*>(As + m * 64 + ((cg ^ (m & 7)) << 3));
            }
#pragma unroll
            for (int b = 0; b < NB; ++b) {
                int n = wave * (16 * NB) + b * 16 + (lane & 15);
                bf[b] = *reinterpret_cast<const half8*>(Bs + n * 64 + ((cg ^ (n & 7)) << 3));
            }
#pragma unroll
            for (int a = 0; a < 4; ++a)
#pragma unroll
                for (int b = 0; b < NB; ++b)
                    acc[a][b] = __builtin_amdgcn_mfma_f32_16x16x32_f16(af[a], bf[b], acc[a][b], 0, 0, 0);
        }
    }

    // ---- epilogue: col = lane&15, row = (lane>>4)*4 + r ----
#pragma unroll
    for (int a = 0; a < 4; ++a) {
        int mrel = a * 16 + ((lane >> 4) << 2);
#pragma unroll
        for (int r = 0; r < 4; ++r) {
            int m = iBase + mrel + r;
            if (m < rows) {
#pragma unroll
                for (int b = 0; b < NB; ++b) {
                    int gcol = nHalf * BN + wave * (16 * NB) + b * 16 + (lane & 15);
                    _Float16* Cout = (gcol < HIDD) ? Cl : Cr;
                    Cout[(size_t)m * HIDD + (gcol & (HIDD - 1))] = (_Float16)acc[a][b][r];
                }
            }
        }
    }
}

// ---------------------------------------------------------------------------
// Reverse-adjacency bucket build.
// ---------------------------------------------------------------------------
__global__ void build_inc(const int* __restrict__ nbr, int* __restrict__ cnt,
                          int* __restrict__ inc, int nEdges) {
    int e = blockIdx.x * blockDim.x + threadIdx.x;
    if (e >= nEdges) return;
    int d = nbr[e];
    int src = e / NEIGHB;
    int pos = atomicAdd(&cnt[d], 1);
    if (pos < CAP) inc[(size_t)d * CAP + pos] = src;
}

// ---------------------------------------------------------------------------
// O[d,:] f16 = relu( mean_{src->d} Hl[src,:] + bias + Hr[d,:] )
// 16 lanes/row (half8 each), 16 rows/block, gather ILP x4 via int4 idx loads.
// ---------------------------------------------------------------------------
__global__ __launch_bounds__(256) void agg_relu(
    const _Float16* __restrict__ Hl, const _Float16* __restrict__ Hr,
    const int* __restrict__ cnt, const int* __restrict__ inc,
    const float* __restrict__ bias, _Float16* __restrict__ O, int N) {
    int d = blockIdx.x * 16 + (threadIdx.x >> 4);
    if (d >= N) return;
    int c8 = (threadIdx.x & 15) * 8;
    int c = cnt[d];
    int cc = min(c, CAP);
    const int* lst = inc + (size_t)d * CAP;
    // early loads (overlap with gather latency)
    half8 hr = *reinterpret_cast<const half8*>(Hr + (size_t)d * HIDD + c8);
    float4 b0 = *reinterpret_cast<const float4*>(bias + c8);
    float4 b1 = *reinterpret_cast<const float4*>(bias + c8 + 4);
    float s[8];
#pragma unroll
    for (int j = 0; j < 8; ++j) s[j] = 0.f;
    int e = 0;
    for (; e + 4 <= cc; e += 4) {
        int4 ii = *reinterpret_cast<const int4*>(lst + e);
        half8 v0 = *reinterpret_cast<const half8*>(Hl + (size_t)ii.x * HIDD + c8);
        half8 v1 = *reinterpret_cast<const half8*>(Hl + (size_t)ii.y * HIDD + c8);
        half8 v2 = *reinterpret_cast<const half8*>(Hl + (size_t)ii.z * HIDD + c8);
        half8 v3 = *reinterpret_cast<const half8*>(Hl + (size_t)ii.w * HIDD + c8);
#pragma unroll
        for (int j = 0; j < 8; ++j)
            s[j] += ((float)v0[j] + (float)v1[j]) + ((float)v2[j] + (float)v3[j]);
    }
    for (; e < cc; ++e) {
        half8 v0 = *reinterpret_cast<const half8*>(Hl + (size_t)lst[e] * HIDD + c8);
#pragma unroll
        for (int j = 0; j < 8; ++j) s[j] += (float)v0[j];
    }
    float inv = 1.f / (float)max(c, 1);
    float bb[8] = {b0.x, b0.y, b0.z, b0.w, b1.x, b1.y, b1.z, b1.w};
    half8 o;
#pragma unroll
    for (int j = 0; j < 8; ++j)
        o[j] = (_Float16)fmaxf(s[j] * inv + bb[j] + (float)hr[j], 0.f);
    *reinterpret_cast<half8*>(O + (size_t)d * HIDD + c8) = o;
}

// ---------------------------------------------------------------------------
// Per-crystal mean pool over concat(bo2, ao2) f16, then 2-class FC.
// ---------------------------------------------------------------------------
__global__ __launch_bounds__(256) void pool_fc(const _Float16* __restrict__ bo,
                                               const _Float16* __restrict__ ao,
                                               const int* __restrict__ crys,
                                               const float* __restrict__ Wfc,
                                               const float* __restrict__ bfc,
                                               float* __restrict__ out) {
    __shared__ float red0[256];
    __shared__ float red1[256];
    int b = blockIdx.x;
    int t = threadIdx.x;
    int s0 = crys[b * 2 + 0];
    int s1 = crys[b * 2 + 1];
    const _Float16* src = (t < HIDD) ? bo : ao;
    int col = t & (HIDD - 1);
    float s = 0.f;
    for (int i = s0; i < s1; ++i) s += (float)src[(size_t)i * HIDD + col];
    float pooled = s / (float)(s1 - s0);
    red0[t] = pooled * Wfc[t];
    red1[t] = pooled * Wfc[256 + t];
    __syncthreads();
    for (int off = 128; off >= 1; off >>= 1) {
        if (t < off) {
            red0[t] += red0[t + off];
            red1[t] += red1[t + off];
        }
        __syncthreads();
    }
    if (t == 0) {
        out[b * 2 + 0] = red0[0] + bfc[0];
        out[b * 2 + 1] = red1[0] + bfc[1];
    }
}

// ---------------------------------------------------------------------------
extern "C" void kernel_launch(void* const* d_in, const int* in_sizes, int n_in,
                              void* d_out, int out_size, void* d_ws, size_t ws_size,
                              hipStream_t stream) {
    const float* bond = (const float*)d_in[0];
    const float* angle = (const float*)d_in[1];
    const int* nbr = (const int*)d_in[3];
    const int* crys = (const int*)d_in[4];
    const float* W1b = (const float*)d_in[5];
    const float* b1b = (const float*)d_in[6];
    const float* W1br = (const float*)d_in[7];
    const float* W1a = (const float*)d_in[8];
    const float* b1a = (const float*)d_in[9];
    const float* W1ar = (const float*)d_in[10];
    const float* W2b = (const float*)d_in[11];
    const float* b2b = (const float*)d_in[12];
    const float* W2br = (const float*)d_in[13];
    const float* W2a = (const float*)d_in[14];
    const float* b2a = (const float*)d_in[15];
    const float* W2ar = (const float*)d_in[16];
    const float* Wfc = (const float*)d_in[17];
    const float* bfc = (const float*)d_in[18];
    float* out = (float*)d_out;

    const int N = in_sizes[2];      // 50000
    const int B = in_sizes[4] / 2;  // 500
    const int nEdges = N * NEIGHB;

    // ---- workspace carve (~86 MB) ----
    char* p = (char*)d_ws;
    _Float16* Hl  = (_Float16*)p;  p += (size_t)N * HIDD * 2;
    _Float16* Hr  = (_Float16*)p;  p += (size_t)N * HIDD * 2;
    _Float16* bo  = (_Float16*)p;  p += (size_t)N * HIDD * 2;
    _Float16* ao  = (_Float16*)p;  p += (size_t)N * HIDD * 2;
    _Float16* bo2 = (_Float16*)p;  p += (size_t)N * HIDD * 2;
    _Float16* ao2 = (_Float16*)p;  p += (size_t)N * HIDD * 2;
    int* cnt = (int*)p;            p += (size_t)N * 4;
    int* inc = (int*)p;            p += (size_t)N * CAP * 4;
    _Float16* W1bp = (_Float16*)p; p += 256 * 512 * 2;
    _Float16* W1ap = (_Float16*)p; p += 256 * 1472 * 2;
    _Float16* W2bp = (_Float16*)p; p += 256 * 128 * 2;
    _Float16* W2ap = (_Float16*)p;

    hipMemsetAsync(cnt, 0, (size_t)N * 4, stream);
    build_inc<<<(nEdges + 255) / 256, 256, 0, stream>>>(nbr, cnt, inc, nEdges);
    cvt_all<<<2240, 256, 0, stream>>>(W1b, W1br, W1bp, W1a, W1ar, W1ap,
                                      W2b, W2br, W2bp, W2a, W2ar, W2ap);

    const int gB = (N + 63) / 64;    // 782
    const int aB = (N + 15) / 16;    // 3125

    // bond layer 1 (fused GBF, raw in LDS, full-N tile)
    gemm_f16<1, 480, 512, 1><<<gB, 256, 0, stream>>>(bond, W1bp, Hl, Hr, N);
    agg_relu<<<aB, 256, 0, stream>>>(Hl, Hr, cnt, inc, b1b, bo, N);
    // angle layer 1 (fused GBF, raw in LDS, N split x2 -> 1564 blocks)
    gemm_f16<2, 1440, 1472, 2><<<gB * 2, 256, 0, stream>>>(angle, W1ap, Hl, Hr, N);
    agg_relu<<<aB, 256, 0, stream>>>(Hl, Hr, cnt, inc, b1a, ao, N);
    // layer 2
    gemm_f16<0, 128, 128, 1><<<gB, 256, 0, stream>>>(bo, W2bp, Hl, Hr, N);
    agg_relu<<<aB, 256, 0, stream>>>(Hl, Hr, cnt, inc, b2b, bo2, N);
    gemm_f16<0, 128, 128, 1><<<gB, 256, 0, stream>>>(ao, W2ap, Hl, Hr, N);
    agg_relu<<<aB, 256, 0, stream>>>(Hl, Hr, cnt, inc, b2a, ao2, N);

    pool_fc<<<B, 256, 0, stream>>>(bo2, ao2, crys, Wfc, bfc, out);
}

// Round 6
// 411.363 us; speedup vs baseline: 1.0942x; 1.0942x over previous
//
#include <hip/hip_runtime.h>

#define NEIGHB 12
#define HIDD 128
#define CAP 40

typedef _Float16 half8 __attribute__((ext_vector_type(8)));
typedef float f32x4 __attribute__((ext_vector_type(4)));

// ---------------------------------------------------------------------------
// One-shot weight convert: 4 pairs (Wl,Wr) f32 -> [256][Kp] f16 zero-padded.
// ---------------------------------------------------------------------------
__global__ __launch_bounds__(256) void cvt_all(
    const float* __restrict__ W1b, const float* __restrict__ W1br, _Float16* __restrict__ O1b,
    const float* __restrict__ W1a, const float* __restrict__ W1ar, _Float16* __restrict__ O1a,
    const float* __restrict__ W2b, const float* __restrict__ W2br, _Float16* __restrict__ O2b,
    const float* __restrict__ W2a, const float* __restrict__ W2ar, _Float16* __restrict__ O2a) {
    int blk = blockIdx.x;
    const float *Wl, *Wr; _Float16* out; int K, Kp, base;
    if (blk < 512)       { Wl = W1b; Wr = W1br; out = O1b; K = 480;  Kp = 512;  base = 0; }
    else if (blk < 1984) { Wl = W1a; Wr = W1ar; out = O1a; K = 1440; Kp = 1472; base = 512; }
    else if (blk < 2112) { Wl = W2b; Wr = W2br; out = O2b; K = 128;  Kp = 128;  base = 1984; }
    else                 { Wl = W2a; Wr = W2ar; out = O2a; K = 128;  Kp = 128;  base = 2112; }
    int idx = (blk - base) * 256 + threadIdx.x;
    int n = idx / Kp, k = idx - n * Kp;
    float v = 0.f;
    if (k < K) v = (n < HIDD) ? Wl[(size_t)n * K + k] : Wr[(size_t)(n - HIDD) * K + k];
    out[idx] = (_Float16)v;
}

// ---------------------------------------------------------------------------
// MFMA GEMM, register-prefetch pipelined, optional fused GBF expansion.
// MODE 0: A = f16 [rows, KP] direct.
// MODE 1: A = gbf(bond f32 [rows,12]),  K=480,  SUB=40 (granule never crosses)
// MODE 2: A = gbf(angle f32 [rows,144]), K=1440, SUB=10 (crosses <= 1)
// Block 256 thr / 4 waves; tile 64(M) x 256(N); wave tile 64x64; BK=64.
// Per thread: row-slot mrow = tid>>3 (and +32), granule g = tid&7 (fixed).
// Pipeline: prefetch tile t+1 (B granules + raw scalars) into regs during
// tile t's MFMA; expansion also in compute phase; stage phase = ds_writes only.
// LDS XOR swizzle: 16B granule g at g ^ (row & 7) (0 conflicts, round-4 PMC).
// ---------------------------------------------------------------------------
template <int MODE, int KTOT, int KP>
__global__ __launch_bounds__(256) void gemm_f16(
    const void* __restrict__ Ain, const _Float16* __restrict__ Wt,
    _Float16* __restrict__ Cl, _Float16* __restrict__ Cr, int rows) {
    constexpr int SUB  = (MODE == 2) ? 10 : 40;
    constexpr int RAWC = (MODE == 2) ? 144 : 12;
    constexpr float MU0 = (MODE == 2) ? -1.0f : 0.0f;
    constexpr float DMU = (MODE == 2) ? (2.0f / 9.0f) : (8.0f / 39.0f);
    constexpr int NT = KP / 64;

    __shared__ __align__(16) _Float16 As[64 * 64];
    __shared__ __align__(16) _Float16 Bs[256 * 64];

    const int tid = threadIdx.x;
    const int lane = tid & 63;
    const int wave = tid >> 6;
    const int iBase = blockIdx.x * 64;
    const int mrow = tid >> 3;      // 0..31
    const int g = tid & 7;          // fixed granule
    const int g8 = g * 8;

    const int gi0 = min(iBase + mrow, rows - 1);
    const int gi1 = min(iBase + mrow + 32, rows - 1);
    const _Float16* Ap = (const _Float16*)Ain;
    const float* rr0 = (const float*)Ain + (size_t)gi0 * RAWC;
    const float* rr1 = (const float*)Ain + (size_t)gi1 * RAWC;

    half8 bReg[8];
    half8 aExp[2];
    float r0v[2], r1v[2];

#define PREFETCH(KC)                                                              \
    {                                                                             \
        _Pragma("unroll")                                                         \
        for (int q = 0; q < 8; ++q)                                               \
            bReg[q] = *reinterpret_cast<const half8*>(                            \
                Wt + (size_t)(mrow + 32 * q) * KP + (KC) + g8);                   \
        if (MODE == 0) {                                                          \
            aExp[0] = *reinterpret_cast<const half8*>(Ap + (size_t)gi0 * KP + (KC) + g8); \
            aExp[1] = *reinterpret_cast<const half8*>(Ap + (size_t)gi1 * KP + (KC) + g8); \
        } else {                                                                  \
            int k0 = (KC) + g8;                                                   \
            if (k0 < KTOT) {                                                      \
                int j0 = k0 / SUB;                                                \
                r0v[0] = rr0[j0]; r0v[1] = rr1[j0];                               \
                if (MODE == 2) {                                                  \
                    int jn = min(j0 + 1, RAWC - 1);                               \
                    r1v[0] = rr0[jn]; r1v[1] = rr1[jn];                           \
                }                                                                 \
            }                                                                     \
        }                                                                         \
    }

#define EXPAND(KC)                                                                \
    if (MODE != 0) {                                                              \
        int k0 = (KC) + g8;                                                       \
        if (k0 < KTOT) {                                                          \
            int j0 = k0 / SUB, t0 = k0 - j0 * SUB;                                \
            _Pragma("unroll")                                                     \
            for (int q = 0; q < 2; ++q) {                                         \
                float ra = r0v[q];                                                \
                float rb = (MODE == 2) ? r1v[q] : r0v[q];                         \
                half8 v;                                                          \
                _Pragma("unroll")                                                 \
                for (int e2 = 0; e2 < 8; ++e2) {                                  \
                    int tt = t0 + e2;                                             \
                    bool c2 = (tt >= SUB);                                        \
                    float dd = (c2 ? rb : ra) -                                   \
                               (MU0 + (float)(c2 ? tt - SUB : tt) * DMU);         \
                    v[e2] = (_Float16)__expf(-25.f * dd * dd);                    \
                }                                                                 \
                aExp[q] = v;                                                      \
            }                                                                     \
        } else {                                                                  \
            _Pragma("unroll")                                                     \
            for (int q = 0; q < 2; ++q) {                                         \
                half8 v;                                                          \
                _Pragma("unroll")                                                 \
                for (int e2 = 0; e2 < 8; ++e2) v[e2] = (_Float16)0.f;             \
                aExp[q] = v;                                                      \
            }                                                                     \
        }                                                                         \
    }

    f32x4 acc[4][4];
#pragma unroll
    for (int a = 0; a < 4; ++a)
#pragma unroll
        for (int b = 0; b < 4; ++b)
#pragma unroll
            for (int r = 0; r < 4; ++r) acc[a][b][r] = 0.f;

    PREFETCH(0);
    EXPAND(0);

#pragma unroll 1
    for (int t = 0; t < NT; ++t) {
        const int kc = t * 64;
        __syncthreads();  // all waves done reading previous tile
        // ---- stage: regs -> LDS (10 ds_write_b128, conflict-free) ----
#pragma unroll
        for (int q = 0; q < 2; ++q) {
            int m = mrow + 32 * q;
            *reinterpret_cast<half8*>(As + m * 64 + ((g ^ (m & 7)) << 3)) = aExp[q];
        }
#pragma unroll
        for (int q = 0; q < 8; ++q) {
            int n = mrow + 32 * q;
            *reinterpret_cast<half8*>(Bs + n * 64 + ((g ^ (n & 7)) << 3)) = bReg[q];
        }
        __syncthreads();  // tile ready
        const bool hasNext = (t + 1) < NT;
        if (hasNext) PREFETCH(kc + 64);
        // ---- compute: 2 sub-steps of K=32, 16 MFMA each ----
#pragma unroll
        for (int s = 0; s < 2; ++s) {
            int cg = s * 4 + (lane >> 4);
            half8 af[4], bf[4];
#pragma unroll
            for (int a = 0; a < 4; ++a) {
                int m = a * 16 + (lane & 15);
                af[a] = *reinterpret_cast<const half8*>(As + m * 64 + ((cg ^ (m & 7)) << 3));
            }
#pragma unroll
            for (int b = 0; b < 4; ++b) {
                int n = wave * 64 + b * 16 + (lane & 15);
                bf[b] = *reinterpret_cast<const half8*>(Bs + n * 64 + ((cg ^ (n & 7)) << 3));
            }
#pragma unroll
            for (int a = 0; a < 4; ++a)
#pragma unroll
                for (int b = 0; b < 4; ++b)
                    acc[a][b] = __builtin_amdgcn_mfma_f32_16x16x32_f16(af[a], bf[b], acc[a][b], 0, 0, 0);
        }
        if (hasNext) EXPAND(kc + 64);
    }
#undef PREFETCH
#undef EXPAND

    // ---- epilogue: col = lane&15, row = (lane>>4)*4 + r ----
    _Float16* Cout = (wave < 2) ? Cl : Cr;
    int nBase = (wave & 1) * 64;
#pragma unroll
    for (int a = 0; a < 4; ++a) {
        int mrel = a * 16 + ((lane >> 4) << 2);
#pragma unroll
        for (int r = 0; r < 4; ++r) {
            int m = iBase + mrel + r;
            if (m < rows) {
#pragma unroll
                for (int b = 0; b < 4; ++b) {
                    int n = nBase + b * 16 + (lane & 15);
                    Cout[(size_t)m * HIDD + n] = (_Float16)acc[a][b][r];
                }
            }
        }
    }
}

// ---------------------------------------------------------------------------
// Reverse-adjacency bucket build.
// ---------------------------------------------------------------------------
__global__ void build_inc(const int* __restrict__ nbr, int* __restrict__ cnt,
                          int* __restrict__ inc, int nEdges) {
    int e = blockIdx.x * blockDim.x + threadIdx.x;
    if (e >= nEdges) return;
    int d = nbr[e];
    int src = e / NEIGHB;
    int pos = atomicAdd(&cnt[d], 1);
    if (pos < CAP) inc[(size_t)d * CAP + pos] = src;
}

// ---------------------------------------------------------------------------
// Dual-stream mean-aggregate + bias + residual + relu.
// Ob[d,:] = relu(mean_{s->d} Hbl[s,:] + biasB + Hbr[d,:]); Oa likewise.
// 16 lanes/row, 16 rows/block. 24 gathers in flight (12 idx, clamped weights);
// dynamic tail for c > 12 (P ~ 38%, short).
// ---------------------------------------------------------------------------
__global__ __launch_bounds__(256) void agg2(
    const _Float16* __restrict__ Hbl, const _Float16* __restrict__ Hbr,
    const _Float16* __restrict__ Hal, const _Float16* __restrict__ Har,
    const int* __restrict__ cnt, const int* __restrict__ inc,
    const float* __restrict__ biasB, const float* __restrict__ biasA,
    _Float16* __restrict__ Ob, _Float16* __restrict__ Oa, int N) {
    int d = blockIdx.x * 16 + (threadIdx.x >> 4);
    if (d >= N) return;
    int c8 = (threadIdx.x & 15) * 8;
    int c = cnt[d];
    int cc = min(c, CAP);
    const int* lst = inc + (size_t)d * CAP;
    int4 q0 = *reinterpret_cast<const int4*>(lst);
    int4 q1 = *reinterpret_cast<const int4*>(lst + 4);
    int4 q2 = *reinterpret_cast<const int4*>(lst + 8);
    int idx[12] = {q0.x, q0.y, q0.z, q0.w, q1.x, q1.y, q1.z, q1.w,
                   q2.x, q2.y, q2.z, q2.w};
    half8 vb[12], va[12];
#pragma unroll
    for (int e = 0; e < 12; ++e) {
        int ii = (e < cc) ? idx[e] : 0;
        vb[e] = *reinterpret_cast<const half8*>(Hbl + (size_t)ii * HIDD + c8);
        va[e] = *reinterpret_cast<const half8*>(Hal + (size_t)ii * HIDD + c8);
    }
    float sb[8], sa[8];
#pragma unroll
    for (int j = 0; j < 8; ++j) { sb[j] = 0.f; sa[j] = 0.f; }
#pragma unroll
    for (int e = 0; e < 12; ++e) {
        float w = (e < cc) ? 1.f : 0.f;
#pragma unroll
        for (int j = 0; j < 8; ++j) {
            sb[j] = fmaf(w, (float)vb[e][j], sb[j]);
            sa[j] = fmaf(w, (float)va[e][j], sa[j]);
        }
    }
    for (int e = 12; e < cc; ++e) {  // rare tail
        int ii = lst[e];
        half8 xb = *reinterpret_cast<const half8*>(Hbl + (size_t)ii * HIDD + c8);
        half8 xa = *reinterpret_cast<const half8*>(Hal + (size_t)ii * HIDD + c8);
#pragma unroll
        for (int j = 0; j < 8; ++j) { sb[j] += (float)xb[j]; sa[j] += (float)xa[j]; }
    }
    float inv = 1.f / (float)max(c, 1);
    half8 rb = *reinterpret_cast<const half8*>(Hbr + (size_t)d * HIDD + c8);
    half8 ra = *reinterpret_cast<const half8*>(Har + (size_t)d * HIDD + c8);
    float4 bb0 = *reinterpret_cast<const float4*>(biasB + c8);
    float4 bb1 = *reinterpret_cast<const float4*>(biasB + c8 + 4);
    float4 ba0 = *reinterpret_cast<const float4*>(biasA + c8);
    float4 ba1 = *reinterpret_cast<const float4*>(biasA + c8 + 4);
    float fb[8] = {bb0.x, bb0.y, bb0.z, bb0.w, bb1.x, bb1.y, bb1.z, bb1.w};
    float fa[8] = {ba0.x, ba0.y, ba0.z, ba0.w, ba1.x, ba1.y, ba1.z, ba1.w};
    half8 ob, oa;
#pragma unroll
    for (int j = 0; j < 8; ++j) {
        ob[j] = (_Float16)fmaxf(sb[j] * inv + fb[j] + (float)rb[j], 0.f);
        oa[j] = (_Float16)fmaxf(sa[j] * inv + fa[j] + (float)ra[j], 0.f);
    }
    *reinterpret_cast<half8*>(Ob + (size_t)d * HIDD + c8) = ob;
    *reinterpret_cast<half8*>(Oa + (size_t)d * HIDD + c8) = oa;
}

// ---------------------------------------------------------------------------
// Per-crystal mean pool over concat(bo2, ao2) f16, then 2-class FC.
// ---------------------------------------------------------------------------
__global__ __launch_bounds__(256) void pool_fc(const _Float16* __restrict__ bo,
                                               const _Float16* __restrict__ ao,
                                               const int* __restrict__ crys,
                                               const float* __restrict__ Wfc,
                                               const float* __restrict__ bfc,
                                               float* __restrict__ out) {
    __shared__ float red0[256];
    __shared__ float red1[256];
    int b = blockIdx.x;
    int t = threadIdx.x;
    int s0 = crys[b * 2 + 0];
    int s1 = crys[b * 2 + 1];
    const _Float16* src = (t < HIDD) ? bo : ao;
    int col = t & (HIDD - 1);
    float s = 0.f;
    for (int i = s0; i < s1; ++i) s += (float)src[(size_t)i * HIDD + col];
    float pooled = s / (float)(s1 - s0);
    red0[t] = pooled * Wfc[t];
    red1[t] = pooled * Wfc[256 + t];
    __syncthreads();
    for (int off = 128; off >= 1; off >>= 1) {
        if (t < off) {
            red0[t] += red0[t + off];
            red1[t] += red1[t + off];
        }
        __syncthreads();
    }
    if (t == 0) {
        out[b * 2 + 0] = red0[0] + bfc[0];
        out[b * 2 + 1] = red1[0] + bfc[1];
    }
}

// ---------------------------------------------------------------------------
extern "C" void kernel_launch(void* const* d_in, const int* in_sizes, int n_in,
                              void* d_out, int out_size, void* d_ws, size_t ws_size,
                              hipStream_t stream) {
    const float* bond = (const float*)d_in[0];
    const float* angle = (const float*)d_in[1];
    const int* nbr = (const int*)d_in[3];
    const int* crys = (const int*)d_in[4];
    const float* W1b = (const float*)d_in[5];
    const float* b1b = (const float*)d_in[6];
    const float* W1br = (const float*)d_in[7];
    const float* W1a = (const float*)d_in[8];
    const float* b1a = (const float*)d_in[9];
    const float* W1ar = (const float*)d_in[10];
    const float* W2b = (const float*)d_in[11];
    const float* b2b = (const float*)d_in[12];
    const float* W2br = (const float*)d_in[13];
    const float* W2a = (const float*)d_in[14];
    const float* b2a = (const float*)d_in[15];
    const float* W2ar = (const float*)d_in[16];
    const float* Wfc = (const float*)d_in[17];
    const float* bfc = (const float*)d_in[18];
    float* out = (float*)d_out;

    const int N = in_sizes[2];      // 50000
    const int B = in_sizes[4] / 2;  // 500
    const int nEdges = N * NEIGHB;

    // ---- workspace carve (~112 MB) ----
    char* p = (char*)d_ws;
    _Float16* Hbl = (_Float16*)p;  p += (size_t)N * HIDD * 2;
    _Float16* Hbr = (_Float16*)p;  p += (size_t)N * HIDD * 2;
    _Float16* Hal = (_Float16*)p;  p += (size_t)N * HIDD * 2;
    _Float16* Har = (_Float16*)p;  p += (size_t)N * HIDD * 2;
    _Float16* bo  = (_Float16*)p;  p += (size_t)N * HIDD * 2;
    _Float16* ao  = (_Float16*)p;  p += (size_t)N * HIDD * 2;
    _Float16* bo2 = (_Float16*)p;  p += (size_t)N * HIDD * 2;
    _Float16* ao2 = (_Float16*)p;  p += (size_t)N * HIDD * 2;
    int* cnt = (int*)p;            p += (size_t)N * 4;
    int* inc = (int*)p;            p += (size_t)N * CAP * 4;
    _Float16* W1bp = (_Float16*)p; p += 256 * 512 * 2;
    _Float16* W1ap = (_Float16*)p; p += 256 * 1472 * 2;
    _Float16* W2bp = (_Float16*)p; p += 256 * 128 * 2;
    _Float16* W2ap = (_Float16*)p;

    hipMemsetAsync(cnt, 0, (size_t)N * 4, stream);
    build_inc<<<(nEdges + 255) / 256, 256, 0, stream>>>(nbr, cnt, inc, nEdges);
    cvt_all<<<2240, 256, 0, stream>>>(W1b, W1br, W1bp, W1a, W1ar, W1ap,
                                      W2b, W2br, W2bp, W2a, W2ar, W2ap);

    const int gB = (N + 63) / 64;    // 782
    const int aB = (N + 15) / 16;    // 3125

    // layer 1 (both GEMMs, then one dual-stream agg)
    gemm_f16<1, 480, 512><<<gB, 256, 0, stream>>>(bond, W1bp, Hbl, Hbr, N);
    gemm_f16<2, 1440, 1472><<<gB, 256, 0, stream>>>(angle, W1ap, Hal, Har, N);
    agg2<<<aB, 256, 0, stream>>>(Hbl, Hbr, Hal, Har, cnt, inc, b1b, b1a, bo, ao, N);
    // layer 2
    gemm_f16<0, 128, 128><<<gB, 256, 0, stream>>>(bo, W2bp, Hbl, Hbr, N);
    gemm_f16<0, 128, 128><<<gB, 256, 0, stream>>>(ao, W2ap, Hal, Har, N);
    agg2<<<aB, 256, 0, stream>>>(Hbl, Hbr, Hal, Har, cnt, inc, b2b, b2a, bo2, ao2, N);

    pool_fc<<<B, 256, 0, stream>>>(bo2, ao2, crys, Wfc, bfc, out);
}

// Round 7
// 410.780 us; speedup vs baseline: 1.0958x; 1.0014x over previous
//
#include <hip/hip_runtime.h>

#define NEIGHB 12
#define HIDD 128
#define CAP 40

typedef _Float16 half8 __attribute__((ext_vector_type(8)));
typedef float f32x4 __attribute__((ext_vector_type(4)));

// ---------------------------------------------------------------------------
// Weight pre-pack: (Wl,Wr) f32 [128][K] -> Wp f16 in MFMA-fragment order:
//   Wp[ ((t*16 + nb)*2 + s)*64 + (g*16 + col) ][8]
// where n = nb*16+col (0..255, <128 = Wl), k = t*64 + s*32 + g*8 + e.
// A wave's B-fragment load is then 64 consecutive 16B chunks (coalesced).
// ---------------------------------------------------------------------------
__global__ __launch_bounds__(256) void cvt_pack(
    const float* __restrict__ W1b, const float* __restrict__ W1br, _Float16* __restrict__ O1b,
    const float* __restrict__ W1a, const float* __restrict__ W1ar, _Float16* __restrict__ O1a,
    const float* __restrict__ W2b, const float* __restrict__ W2br, _Float16* __restrict__ O2b,
    const float* __restrict__ W2a, const float* __restrict__ W2ar, _Float16* __restrict__ O2a) {
    int blk = blockIdx.x;
    const float *Wl, *Wr; _Float16* out; int K, Kp, base;
    if (blk < 512)       { Wl = W1b; Wr = W1br; out = O1b; K = 480;  Kp = 512;  base = 0; }
    else if (blk < 1984) { Wl = W1a; Wr = W1ar; out = O1a; K = 1440; Kp = 1472; base = 512; }
    else if (blk < 2112) { Wl = W2b; Wr = W2br; out = O2b; K = 128;  Kp = 128;  base = 1984; }
    else                 { Wl = W2a; Wr = W2ar; out = O2a; K = 128;  Kp = 128;  base = 2112; }
    int idx = (blk - base) * 256 + threadIdx.x;
    int n = idx / Kp, k = idx - n * Kp;
    float v = 0.f;
    if (k < K) v = (n < HIDD) ? Wl[(size_t)n * K + k] : Wr[(size_t)(n - HIDD) * K + k];
    int t = k >> 6, s = (k >> 5) & 1, g = (k >> 3) & 3, e = k & 7;
    int nb = n >> 4, col = n & 15;
    size_t addr = ((((size_t)t * 16 + nb) * 2 + s) * 64 + (g * 16 + col)) * 8 + e;
    out[addr] = (_Float16)v;
}

// ---------------------------------------------------------------------------
// GEMM body: C[i,0:256] = A @ [Wl|Wr]^T.  B entirely in registers (packed Wp,
// double-buffered bA/bB). LDS holds only the A tile (2 x 8KB double buffer,
// XOR swizzle g^(m&7), one barrier per K-step).
// MODE 0: A f16 direct. MODE 1: gbf(bond[.,12]) K=480. MODE 2: gbf(angle[.,144]) K=1440.
// ---------------------------------------------------------------------------
template <int MODE, int KTOT, int KP>
__device__ __forceinline__ void gemm_body(
    const void* __restrict__ Ain, const _Float16* __restrict__ Wp,
    _Float16* __restrict__ Cl, _Float16* __restrict__ Cr,
    int rows, int mb, _Float16* As) {
    constexpr int SUB  = (MODE == 2) ? 10 : 40;
    constexpr int RAWC = (MODE == 2) ? 144 : 12;
    constexpr float MU0 = (MODE == 2) ? -1.0f : 0.0f;
    constexpr float DMU = (MODE == 2) ? (2.0f / 9.0f) : (8.0f / 39.0f);
    constexpr int NT = KP / 64;

    const int tid = threadIdx.x;
    const int lane = tid & 63;
    const int wave = tid >> 6;
    const int iBase = mb * 64;
    const int mrow = tid >> 3;   // 0..31
    const int g = tid & 7;       // fixed granule slot
    const int g8 = g * 8;

    const int gi0 = min(iBase + mrow, rows - 1);
    const int gi1 = min(iBase + mrow + 32, rows - 1);
    const _Float16* Ap = (const _Float16*)Ain;
    const float* rr0 = (const float*)Ain + (size_t)gi0 * RAWC;
    const float* rr1 = (const float*)Ain + (size_t)gi1 * RAWC;

    half8 bA[8], bB[8], aExp[2];
    float r0v[2], r1v[2];

#define PREFB(T, DST)                                                             \
    {                                                                             \
        _Pragma("unroll")                                                         \
        for (int q = 0; q < 8; ++q) {                                             \
            int s_ = q >> 2, b_ = q & 3;                                          \
            (DST)[q] = *reinterpret_cast<const half8*>(                           \
                Wp + ((((size_t)(T) * 16 + (wave * 4 + b_)) * 2 + s_) * 64 + lane) * 8); \
        }                                                                         \
    }

#define LOADA(T)                                                                  \
    {                                                                             \
        if (MODE == 0) {                                                          \
            aExp[0] = *reinterpret_cast<const half8*>(Ap + (size_t)gi0 * KP + (T) * 64 + g8); \
            aExp[1] = *reinterpret_cast<const half8*>(Ap + (size_t)gi1 * KP + (T) * 64 + g8); \
        } else {                                                                  \
            int k0 = (T) * 64 + g8;                                               \
            if (k0 < KTOT) {                                                      \
                int j0 = k0 / SUB;                                                \
                r0v[0] = rr0[j0]; r0v[1] = rr1[j0];                               \
                if (MODE == 2) {                                                  \
                    int jn = min(j0 + 1, RAWC - 1);                               \
                    r1v[0] = rr0[jn]; r1v[1] = rr1[jn];                           \
                }                                                                 \
            }                                                                     \
        }                                                                         \
    }

#define EXPAND(T)                                                                 \
    if (MODE != 0) {                                                              \
        int k0 = (T) * 64 + g8;                                                   \
        if (k0 < KTOT) {                                                          \
            int j0 = k0 / SUB, t0 = k0 - j0 * SUB;                                \
            _Pragma("unroll")                                                     \
            for (int q = 0; q < 2; ++q) {                                         \
                float ra = r0v[q];                                                \
                float rb = (MODE == 2) ? r1v[q] : r0v[q];                         \
                half8 v;                                                          \
                _Pragma("unroll")                                                 \
                for (int e2 = 0; e2 < 8; ++e2) {                                  \
                    int tt = t0 + e2;                                             \
                    bool c2 = (tt >= SUB);                                        \
                    float dd = (c2 ? rb : ra) -                                   \
                               (MU0 + (float)(c2 ? tt - SUB : tt) * DMU);         \
                    v[e2] = (_Float16)__expf(-25.f * dd * dd);                    \
                }                                                                 \
                aExp[q] = v;                                                      \
            }                                                                     \
        } else {                                                                  \
            _Pragma("unroll")                                                     \
            for (int q = 0; q < 2; ++q) {                                         \
                half8 v;                                                          \
                _Pragma("unroll")                                                 \
                for (int e2 = 0; e2 < 8; ++e2) v[e2] = (_Float16)0.f;             \
                aExp[q] = v;                                                      \
            }                                                                     \
        }                                                                         \
    }

#define WRAS(BUF)                                                                 \
    {                                                                             \
        _Pragma("unroll")                                                         \
        for (int q = 0; q < 2; ++q) {                                             \
            int m_ = mrow + 32 * q;                                               \
            *reinterpret_cast<half8*>(As + (BUF) * 4096 + m_ * 64 +               \
                                      ((g ^ (m_ & 7)) << 3)) = aExp[q];           \
        }                                                                         \
    }

#define COMPUTE(BUF, BREG)                                                        \
    {                                                                             \
        _Pragma("unroll")                                                         \
        for (int s_ = 0; s_ < 2; ++s_) {                                          \
            int cg = s_ * 4 + (lane >> 4);                                        \
            half8 af[4];                                                          \
            _Pragma("unroll")                                                     \
            for (int a_ = 0; a_ < 4; ++a_) {                                      \
                int m_ = a_ * 16 + (lane & 15);                                   \
                af[a_] = *reinterpret_cast<const half8*>(                         \
                    As + (BUF) * 4096 + m_ * 64 + ((cg ^ (m_ & 7)) << 3));        \
            }                                                                     \
            _Pragma("unroll")                                                     \
            for (int a_ = 0; a_ < 4; ++a_)                                        \
                _Pragma("unroll")                                                 \
                for (int b_ = 0; b_ < 4; ++b_)                                    \
                    acc[a_][b_] = __builtin_amdgcn_mfma_f32_16x16x32_f16(         \
                        af[a_], (BREG)[s_ * 4 + b_], acc[a_][b_], 0, 0, 0);       \
        }                                                                         \
    }

#define STEP(T, BCUR, BNEXT)                                                      \
    {                                                                             \
        __syncthreads();                                                          \
        const bool hn = (T) + 1 < NT;                                             \
        if (hn) { PREFB((T) + 1, BNEXT); LOADA((T) + 1); }                        \
        COMPUTE((T) & 1, BCUR);                                                   \
        if (hn) { EXPAND((T) + 1); WRAS(((T) + 1) & 1); }                         \
    }

    f32x4 acc[4][4];
#pragma unroll
    for (int a = 0; a < 4; ++a)
#pragma unroll
        for (int b = 0; b < 4; ++b)
#pragma unroll
            for (int r = 0; r < 4; ++r) acc[a][b][r] = 0.f;

    PREFB(0, bA);
    LOADA(0);
    EXPAND(0);
    WRAS(0);

#pragma unroll 1
    for (int t = 0; t < NT; t += 2) {
        STEP(t, bA, bB);
        if (t + 1 < NT) STEP(t + 1, bB, bA);
    }
#undef PREFB
#undef LOADA
#undef EXPAND
#undef WRAS
#undef COMPUTE
#undef STEP

    // ---- epilogue: col = lane&15, row = (lane>>4)*4 + r ----
    _Float16* Cout = (wave < 2) ? Cl : Cr;
    int nBase = (wave & 1) * 64;
#pragma unroll
    for (int a = 0; a < 4; ++a) {
        int mrel = a * 16 + ((lane >> 4) << 2);
#pragma unroll
        for (int r = 0; r < 4; ++r) {
            int m = iBase + mrel + r;
            if (m < rows) {
#pragma unroll
                for (int b = 0; b < 4; ++b) {
                    int n = nBase + b * 16 + (lane & 15);
                    Cout[(size_t)m * HIDD + n] = (_Float16)acc[a][b][r];
                }
            }
        }
    }
}

// ---------------------------------------------------------------------------
// Layer-1 merged launch: angle blocks first (long jobs), bond blocks backfill.
// ---------------------------------------------------------------------------
__global__ __launch_bounds__(256) void gemm_l1(
    const float* __restrict__ bond, const _Float16* __restrict__ Wb,
    _Float16* __restrict__ Hbl, _Float16* __restrict__ Hbr,
    const float* __restrict__ angle, const _Float16* __restrict__ Wa,
    _Float16* __restrict__ Hal, _Float16* __restrict__ Har, int rows, int aGB) {
    __shared__ __align__(16) _Float16 As[2 * 64 * 64];
    if ((int)blockIdx.x < aGB)
        gemm_body<2, 1440, 1472>(angle, Wa, Hal, Har, rows, blockIdx.x, As);
    else
        gemm_body<1, 480, 512>(bond, Wb, Hbl, Hbr, rows, blockIdx.x - aGB, As);
}

// ---------------------------------------------------------------------------
// Layer-2 merged launch: blockIdx.y = 0 -> bond stream, 1 -> angle stream.
// ---------------------------------------------------------------------------
__global__ __launch_bounds__(256) void gemm_l2(
    const _Float16* __restrict__ bo, const _Float16* __restrict__ Wb,
    _Float16* __restrict__ Hbl, _Float16* __restrict__ Hbr,
    const _Float16* __restrict__ ao, const _Float16* __restrict__ Wa,
    _Float16* __restrict__ Hal, _Float16* __restrict__ Har, int rows) {
    __shared__ __align__(16) _Float16 As[2 * 64 * 64];
    if (blockIdx.y == 0)
        gemm_body<0, 128, 128>(bo, Wb, Hbl, Hbr, rows, blockIdx.x, As);
    else
        gemm_body<0, 128, 128>(ao, Wa, Hal, Har, rows, blockIdx.x, As);
}

// ---------------------------------------------------------------------------
// Reverse-adjacency bucket build.
// ---------------------------------------------------------------------------
__global__ void build_inc(const int* __restrict__ nbr, int* __restrict__ cnt,
                          int* __restrict__ inc, int nEdges) {
    int e = blockIdx.x * blockDim.x + threadIdx.x;
    if (e >= nEdges) return;
    int d = nbr[e];
    int src = e / NEIGHB;
    int pos = atomicAdd(&cnt[d], 1);
    if (pos < CAP) inc[(size_t)d * CAP + pos] = src;
}

// ---------------------------------------------------------------------------
// Dual-stream mean-aggregate + bias + residual + relu.
// ---------------------------------------------------------------------------
__global__ __launch_bounds__(256) void agg2(
    const _Float16* __restrict__ Hbl, const _Float16* __restrict__ Hbr,
    const _Float16* __restrict__ Hal, const _Float16* __restrict__ Har,
    const int* __restrict__ cnt, const int* __restrict__ inc,
    const float* __restrict__ biasB, const float* __restrict__ biasA,
    _Float16* __restrict__ Ob, _Float16* __restrict__ Oa, int N) {
    int d = blockIdx.x * 16 + (threadIdx.x >> 4);
    if (d >= N) return;
    int c8 = (threadIdx.x & 15) * 8;
    int c = cnt[d];
    int cc = min(c, CAP);
    const int* lst = inc + (size_t)d * CAP;
    int4 q0 = *reinterpret_cast<const int4*>(lst);
    int4 q1 = *reinterpret_cast<const int4*>(lst + 4);
    int4 q2 = *reinterpret_cast<const int4*>(lst + 8);
    int idx[12] = {q0.x, q0.y, q0.z, q0.w, q1.x, q1.y, q1.z, q1.w,
                   q2.x, q2.y, q2.z, q2.w};
    half8 vb[12], va[12];
#pragma unroll
    for (int e = 0; e < 12; ++e) {
        int ii = (e < cc) ? idx[e] : 0;
        vb[e] = *reinterpret_cast<const half8*>(Hbl + (size_t)ii * HIDD + c8);
        va[e] = *reinterpret_cast<const half8*>(Hal + (size_t)ii * HIDD + c8);
    }
    float sb[8], sa[8];
#pragma unroll
    for (int j = 0; j < 8; ++j) { sb[j] = 0.f; sa[j] = 0.f; }
#pragma unroll
    for (int e = 0; e < 12; ++e) {
        float w = (e < cc) ? 1.f : 0.f;
#pragma unroll
        for (int j = 0; j < 8; ++j) {
            sb[j] = fmaf(w, (float)vb[e][j], sb[j]);
            sa[j] = fmaf(w, (float)va[e][j], sa[j]);
        }
    }
    for (int e = 12; e < cc; ++e) {
        int ii = lst[e];
        half8 xb = *reinterpret_cast<const half8*>(Hbl + (size_t)ii * HIDD + c8);
        half8 xa = *reinterpret_cast<const half8*>(Hal + (size_t)ii * HIDD + c8);
#pragma unroll
        for (int j = 0; j < 8; ++j) { sb[j] += (float)xb[j]; sa[j] += (float)xa[j]; }
    }
    float inv = 1.f / (float)max(c, 1);
    half8 rb = *reinterpret_cast<const half8*>(Hbr + (size_t)d * HIDD + c8);
    half8 ra = *reinterpret_cast<const half8*>(Har + (size_t)d * HIDD + c8);
    float4 bb0 = *reinterpret_cast<const float4*>(biasB + c8);
    float4 bb1 = *reinterpret_cast<const float4*>(biasB + c8 + 4);
    float4 ba0 = *reinterpret_cast<const float4*>(biasA + c8);
    float4 ba1 = *reinterpret_cast<const float4*>(biasA + c8 + 4);
    float fb[8] = {bb0.x, bb0.y, bb0.z, bb0.w, bb1.x, bb1.y, bb1.z, bb1.w};
    float fa[8] = {ba0.x, ba0.y, ba0.z, ba0.w, ba1.x, ba1.y, ba1.z, ba1.w};
    half8 ob, oa;
#pragma unroll
    for (int j = 0; j < 8; ++j) {
        ob[j] = (_Float16)fmaxf(sb[j] * inv + fb[j] + (float)rb[j], 0.f);
        oa[j] = (_Float16)fmaxf(sa[j] * inv + fa[j] + (float)ra[j], 0.f);
    }
    *reinterpret_cast<half8*>(Ob + (size_t)d * HIDD + c8) = ob;
    *reinterpret_cast<half8*>(Oa + (size_t)d * HIDD + c8) = oa;
}

// ---------------------------------------------------------------------------
// Per-crystal mean pool over concat(bo2, ao2) f16, then 2-class FC.
// ---------------------------------------------------------------------------
__global__ __launch_bounds__(256) void pool_fc(const _Float16* __restrict__ bo,
                                               const _Float16* __restrict__ ao,
                                               const int* __restrict__ crys,
                                               const float* __restrict__ Wfc,
                                               const float* __restrict__ bfc,
                                               float* __restrict__ out) {
    __shared__ float red0[256];
    __shared__ float red1[256];
    int b = blockIdx.x;
    int t = threadIdx.x;
    int s0 = crys[b * 2 + 0];
    int s1 = crys[b * 2 + 1];
    const _Float16* src = (t < HIDD) ? bo : ao;
    int col = t & (HIDD - 1);
    float s = 0.f;
    for (int i = s0; i < s1; ++i) s += (float)src[(size_t)i * HIDD + col];
    float pooled = s / (float)(s1 - s0);
    red0[t] = pooled * Wfc[t];
    red1[t] = pooled * Wfc[256 + t];
    __syncthreads();
    for (int off = 128; off >= 1; off >>= 1) {
        if (t < off) {
            red0[t] += red0[t + off];
            red1[t] += red1[t + off];
        }
        __syncthreads();
    }
    if (t == 0) {
        out[b * 2 + 0] = red0[0] + bfc[0];
        out[b * 2 + 1] = red1[0] + bfc[1];
    }
}

// ---------------------------------------------------------------------------
extern "C" void kernel_launch(void* const* d_in, const int* in_sizes, int n_in,
                              void* d_out, int out_size, void* d_ws, size_t ws_size,
                              hipStream_t stream) {
    const float* bond = (const float*)d_in[0];
    const float* angle = (const float*)d_in[1];
    const int* nbr = (const int*)d_in[3];
    const int* crys = (const int*)d_in[4];
    const float* W1b = (const float*)d_in[5];
    const float* b1b = (const float*)d_in[6];
    const float* W1br = (const float*)d_in[7];
    const float* W1a = (const float*)d_in[8];
    const float* b1a = (const float*)d_in[9];
    const float* W1ar = (const float*)d_in[10];
    const float* W2b = (const float*)d_in[11];
    const float* b2b = (const float*)d_in[12];
    const float* W2br = (const float*)d_in[13];
    const float* W2a = (const float*)d_in[14];
    const float* b2a = (const float*)d_in[15];
    const float* W2ar = (const float*)d_in[16];
    const float* Wfc = (const float*)d_in[17];
    const float* bfc = (const float*)d_in[18];
    float* out = (float*)d_out;

    const int N = in_sizes[2];      // 50000
    const int B = in_sizes[4] / 2;  // 500
    const int nEdges = N * NEIGHB;

    // ---- workspace carve (~112 MB) ----
    char* p = (char*)d_ws;
    _Float16* Hbl = (_Float16*)p;  p += (size_t)N * HIDD * 2;
    _Float16* Hbr = (_Float16*)p;  p += (size_t)N * HIDD * 2;
    _Float16* Hal = (_Float16*)p;  p += (size_t)N * HIDD * 2;
    _Float16* Har = (_Float16*)p;  p += (size_t)N * HIDD * 2;
    _Float16* bo  = (_Float16*)p;  p += (size_t)N * HIDD * 2;
    _Float16* ao  = (_Float16*)p;  p += (size_t)N * HIDD * 2;
    _Float16* bo2 = (_Float16*)p;  p += (size_t)N * HIDD * 2;
    _Float16* ao2 = (_Float16*)p;  p += (size_t)N * HIDD * 2;
    int* cnt = (int*)p;            p += (size_t)N * 4;
    int* inc = (int*)p;            p += (size_t)N * CAP * 4;
    _Float16* W1bp = (_Float16*)p; p += 256 * 512 * 2;
    _Float16* W1ap = (_Float16*)p; p += 256 * 1472 * 2;
    _Float16* W2bp = (_Float16*)p; p += 256 * 128 * 2;
    _Float16* W2ap = (_Float16*)p;

    hipMemsetAsync(cnt, 0, (size_t)N * 4, stream);
    build_inc<<<(nEdges + 255) / 256, 256, 0, stream>>>(nbr, cnt, inc, nEdges);
    cvt_pack<<<2240, 256, 0, stream>>>(W1b, W1br, W1bp, W1a, W1ar, W1ap,
                                       W2b, W2br, W2bp, W2a, W2ar, W2ap);

    const int gB = (N + 63) / 64;    // 782
    const int aB = (N + 15) / 16;    // 3125

    // layer 1: one merged launch (angle first, bond backfills), then agg
    gemm_l1<<<gB * 2, 256, 0, stream>>>(bond, W1bp, Hbl, Hbr,
                                        angle, W1ap, Hal, Har, N, gB);
    agg2<<<aB, 256, 0, stream>>>(Hbl, Hbr, Hal, Har, cnt, inc, b1b, b1a, bo, ao, N);
    // layer 2: one merged launch (y = stream), then agg
    gemm_l2<<<dim3(gB, 2), 256, 0, stream>>>(bo, W2bp, Hbl, Hbr,
                                             ao, W2ap, Hal, Har, N);
    agg2<<<aB, 256, 0, stream>>>(Hbl, Hbr, Hal, Har, cnt, inc, b2b, b2a, bo2, ao2, N);

    pool_fc<<<B, 256, 0, stream>>>(bo2, ao2, crys, Wfc, bfc, out);
}